// Round 2
// baseline (2258.101 us; speedup 1.0000x reference)
//
#include <hip/hip_runtime.h>

#define BB 4
#define NN 8192
#define SS 1024

// ---- exact-IEEE helpers (no FMA contraction: must match numpy fp32 refs) ----
static __device__ __forceinline__ float sq3(float x, float y, float z) {
  return __fadd_rn(__fadd_rn(__fmul_rn(x, x), __fmul_rn(y, y)), __fmul_rn(z, z));
}

// ============================ Kernel A: prep =================================
// SoA split of pcd + per-point squared norm (exact op order: (x^2+y^2)+z^2)
__global__ void prep_kernel(const float* __restrict__ pcd,
                            float* __restrict__ xs, float* __restrict__ ys,
                            float* __restrict__ zs, float* __restrict__ sp) {
  int i = blockIdx.x * 256 + threadIdx.x;
  if (i < BB * NN) {
    float x = pcd[3 * i], y = pcd[3 * i + 1], z = pcd[3 * i + 2];
    xs[i] = x; ys[i] = y; zs[i] = z;
    sp[i] = sq3(x, y, z);
  }
}

// ============================ Kernel B: FPS ==================================
// One block per batch. 512 threads x 16 points in registers.
// Exactly replicates: dist = min(dist, ||p - c||^2) (plain fp32 ops, no FMA:
// the reference materializes (xyz-c)**2 before the reduce, so no contraction),
// far = argmax(dist) with first-index tie-break; emits far BEFORE update.
__global__ __launch_bounds__(512) void fps_kernel(const float* __restrict__ pcd,
                                                  float* __restrict__ new_xyz,
                                                  float* __restrict__ s_new) {
  const int b = blockIdx.x;
  const float* P = pcd + (size_t)b * NN * 3;
  __shared__ float csh[3];
  __shared__ float wmaxs[8];
  __shared__ int widxs[8];

  float lx[16], ly[16], lz[16], dst[16];
  const int base = threadIdx.x * 16;
#pragma unroll
  for (int k = 0; k < 16; ++k) {
    lx[k] = P[3 * (base + k)];
    ly[k] = P[3 * (base + k) + 1];
    lz[k] = P[3 * (base + k) + 2];
    dst[k] = 1e10f;
  }
  if (threadIdx.x == 0) { csh[0] = P[0]; csh[1] = P[1]; csh[2] = P[2]; }
  __syncthreads();

  for (int t = 0; t < SS; ++t) {
    float cx = csh[0], cy = csh[1], cz = csh[2];
    if (threadIdx.x == 0) {
      float* nx = new_xyz + 3 * (b * SS + t);
      nx[0] = cx; nx[1] = cy; nx[2] = cz;
      s_new[b * SS + t] = sq3(cx, cy, cz);
    }
    float lmax = -1.0f;
    int lidx = 0x7fffffff;
#pragma unroll
    for (int k = 0; k < 16; ++k) {
      float dx = __fsub_rn(lx[k], cx);
      float dy = __fsub_rn(ly[k], cy);
      float dz = __fsub_rn(lz[k], cz);
      float d = __fadd_rn(__fadd_rn(__fmul_rn(dx, dx), __fmul_rn(dy, dy)),
                          __fmul_rn(dz, dz));
      d = fminf(dst[k], d);
      dst[k] = d;
      if (d > lmax) { lmax = d; lidx = base + k; }  // ascending k -> first max
    }
    // wave-level (max, min-idx) butterfly (associative+commutative)
#pragma unroll
    for (int off = 32; off > 0; off >>= 1) {
      float ov = __shfl_xor(lmax, off, 64);
      int oi = __shfl_xor(lidx, off, 64);
      if (ov > lmax || (ov == lmax && oi < lidx)) { lmax = ov; lidx = oi; }
    }
    if ((threadIdx.x & 63) == 0) {
      wmaxs[threadIdx.x >> 6] = lmax;
      widxs[threadIdx.x >> 6] = lidx;
    }
    __syncthreads();
    float gm = wmaxs[0];
    int gi = widxs[0];
#pragma unroll
    for (int w = 1; w < 8; ++w) {
      float v = wmaxs[w];
      int i2 = widxs[w];
      if (v > gm || (v == gm && i2 < gi)) { gm = v; gi = i2; }
    }
    // owner of new far point publishes its coords
    if (gi >= base && gi < base + 16) {
      int k = gi - base;
      csh[0] = lx[k]; csh[1] = ly[k]; csh[2] = lz[k];
    }
    __syncthreads();
  }
}

// ===================== Kernel C: ball query + MLP + head =====================
struct KCParams {
  const float* xs; const float* ys; const float* zs; const float* sp;
  const float* new_xyz; const float* s_new;
  const float* wA[3]; const float* bA[3];
  const float* wB[3]; const float* bB[3];
  const float* wC[3]; const float* bC[3];
  const float* w_out; const float* b_out;
  float* out;
};

template <int NS, int C1, int C2, int C3>
__device__ __forceinline__ void run_branch(
    int tid, int off, int fbase,
    const float* __restrict__ xs, const float* __restrict__ ys,
    const float* __restrict__ zs, float cx, float cy, float cz,
    const float* __restrict__ wA, const float* __restrict__ bA,
    const float* __restrict__ wB, const float* __restrict__ bB,
    const float* __restrict__ wC, const float* __restrict__ bC,
    const int* sidx, float (*g)[4], float (*h1)[36], float (*h2)[52],
    float (*redm)[64], float* feats) {
  // gather (grouped - center): continuous op, FMA-free not required
  if (tid < NS) {
    int ip = sidx[off + tid];
    g[tid][0] = xs[ip] - cx;
    g[tid][1] = ys[ip] - cy;
    g[tid][2] = zs[ip] - cz;
  }
  __syncthreads();
  // L1: 3 -> C1, thread = (channel, sample-group)
  {
    const int cc = tid % C1, sg = tid / C1;
    const int G = 128 / C1;
    float wx = wA[cc], wy = wA[C1 + cc], wz = wA[2 * C1 + cc], bb = bA[cc];
    for (int s0 = sg; s0 < NS; s0 += G) {
      float acc = fmaf(g[s0][0], wx, fmaf(g[s0][1], wy, fmaf(g[s0][2], wz, bb)));
      h1[s0][cc] = fmaxf(acc, 0.0f);
    }
  }
  __syncthreads();
  // L2: C1 -> C2, weights in registers, h1 rows broadcast via float4
  {
    const int G = 128 / C2;
    if (tid < G * C2) {
      const int cc = tid % C2, sg = tid / C2;
      float wr[C1];
#pragma unroll
      for (int k = 0; k < C1; ++k) wr[k] = wB[k * C2 + cc];
      float bb = bB[cc];
#pragma unroll 2
      for (int s0 = sg; s0 < NS; s0 += G) {
        const float4* hr = (const float4*)(&h1[s0][0]);
        float acc = bb;
#pragma unroll
        for (int k4 = 0; k4 < C1 / 4; ++k4) {
          float4 hv = hr[k4];
          acc = fmaf(hv.x, wr[4 * k4 + 0], acc);
          acc = fmaf(hv.y, wr[4 * k4 + 1], acc);
          acc = fmaf(hv.z, wr[4 * k4 + 2], acc);
          acc = fmaf(hv.w, wr[4 * k4 + 3], acc);
        }
        h2[s0][cc] = fmaxf(acc, 0.0f);
      }
    }
  }
  __syncthreads();
  // L3 + maxpool over samples: thread owns an output channel
  {
    const int G = 128 / C3;
    const int cc = tid % C3, sg = tid / C3;
    float wr[C2];
#pragma unroll
    for (int k = 0; k < C2; ++k) wr[k] = wC[k * C3 + cc];
    float bb = bC[cc];
    float pm = -1e30f;
#pragma unroll 2
    for (int s0 = sg; s0 < NS; s0 += G) {
      const float4* hr = (const float4*)(&h2[s0][0]);
      float acc = bb;
#pragma unroll
      for (int k4 = 0; k4 < C2 / 4; ++k4) {
        float4 hv = hr[k4];
        acc = fmaf(hv.x, wr[4 * k4 + 0], acc);
        acc = fmaf(hv.y, wr[4 * k4 + 1], acc);
        acc = fmaf(hv.z, wr[4 * k4 + 2], acc);
        acc = fmaf(hv.w, wr[4 * k4 + 3], acc);
      }
      pm = fmaxf(pm, fmaxf(acc, 0.0f));
    }
    redm[sg][cc] = pm;
  }
  __syncthreads();
  if (tid < C3) {
    float m = redm[0][tid];
#pragma unroll
    for (int gg = 1; gg < 128 / C3; ++gg) m = fmaxf(m, redm[gg][tid]);
    feats[fbase + tid] = m;
  }
  __syncthreads();
}

__global__ __launch_bounds__(128) void sa_kernel(KCParams p) {
  const int bid = blockIdx.x;
  const int b = bid >> 10;
  const int tid = threadIdx.x;
  const int lane = tid & 63;
  const int wv = tid >> 6;

  __shared__ __align__(16) float g[128][4];
  __shared__ __align__(16) float h1s[128][36];
  __shared__ __align__(16) float h2s[128][52];
  __shared__ int sidx[176];
  __shared__ int lid0[2][16];
  __shared__ int lid1[2][32];
  __shared__ int lid2[2][128];
  __shared__ int scnt[2][3];
  __shared__ float feats[160];
  __shared__ __align__(16) float redm[4][64];
  __shared__ float rsum[2];

  const float* xs = p.xs + b * NN;
  const float* ys = p.ys + b * NN;
  const float* zs = p.zs + b * NN;
  const float* sp = p.sp + b * NN;
  const float cx = p.new_xyz[3 * bid];
  const float cy = p.new_xyz[3 * bid + 1];
  const float cz = p.new_xyz[3 * bid + 2];
  const float snew = p.s_new[bid];

  // ---- ball query: two waves scan the two halves, ordered compaction ----
  {
    const float R2_0 = (float)(0.1 * 0.1);
    const float R2_1 = (float)(0.2 * 0.2);
    const float R2_2 = (float)(0.4 * 0.4);
    const unsigned long long below = (1ull << lane) - 1ull;
    int c0 = 0, c1 = 0, c2 = 0;
    int pt = wv * 4096 + lane;
    float x = xs[pt], y = ys[pt], z = zs[pt], s2v = sp[pt];
    for (int it = 0; it < 64; ++it) {
      float xx = x, yy = y, zz = z, ss = s2v;
      if (it < 63) {  // one-deep prefetch
        int q = pt + 64;
        x = xs[q]; y = ys[q]; z = zs[q]; s2v = sp[q];
      }
      // Reference einsum('bsd,bnd->bsn') contraction (K=3) is computed with
      // FMA on every candidate backend (numpy npyv_muladd / Eigen / cublas):
      //   dot = fma(z*cz, fma(y*cy, rn(x*cx)))
      // while the norm sums are materialized-then-reduced (no FMA).
      float dt = fmaf(zz, cz, fmaf(yy, cy, __fmul_rn(xx, cx)));
      float d = __fsub_rn(__fadd_rn(snew, ss), __fmul_rn(2.0f, dt));
      bool m2 = d <= R2_2;
      unsigned long long bm = __ballot(m2);
      if (m2) { int r = c2 + __popcll(bm & below); if (r < 128) lid2[wv][r] = pt; }
      c2 += __popcll(bm);
      bool m1 = d <= R2_1;
      bm = __ballot(m1);
      if (m1) { int r = c1 + __popcll(bm & below); if (r < 32) lid1[wv][r] = pt; }
      c1 += __popcll(bm);
      bool m0 = d <= R2_0;
      bm = __ballot(m0);
      if (m0) { int r = c0 + __popcll(bm & below); if (r < 16) lid0[wv][r] = pt; }
      c0 += __popcll(bm);
      pt += 64;
      if (c0 >= 16 && c1 >= 32 && c2 >= 128) break;
    }
    if (lane == 0) {
      scnt[wv][0] = c0 < 16 ? c0 : 16;
      scnt[wv][1] = c1 < 32 ? c1 : 32;
      scnt[wv][2] = c2 < 128 ? c2 : 128;
    }
  }
  __syncthreads();
  // merge the two halves' ordered lists; pad with first match
  {
    int a0 = scnt[0][0], a1 = scnt[0][1], a2 = scnt[0][2];
    int b0 = scnt[1][0], b1 = scnt[1][1], b2 = scnt[1][2];
    int n0 = min(a0 + b0, 16), n1 = min(a1 + b1, 32), n2 = min(a2 + b2, 128);
    int f0 = a0 ? lid0[0][0] : lid0[1][0];
    int f1 = a1 ? lid1[0][0] : lid1[1][0];
    int f2 = a2 ? lid2[0][0] : lid2[1][0];
    for (int j = tid; j < 176; j += 128) {
      int v;
      if (j < 16) {
        int sl = j;
        v = sl < a0 ? lid0[0][sl] : (sl < n0 ? lid0[1][sl - a0] : f0);
      } else if (j < 48) {
        int sl = j - 16;
        v = sl < a1 ? lid1[0][sl] : (sl < n1 ? lid1[1][sl - a1] : f1);
      } else {
        int sl = j - 48;
        v = sl < a2 ? lid2[0][sl] : (sl < n2 ? lid2[1][sl - a2] : f2);
      }
      sidx[j] = v;
    }
  }
  __syncthreads();

  run_branch<16, 16, 16, 32>(tid, 0, 0, xs, ys, zs, cx, cy, cz,
                             p.wA[0], p.bA[0], p.wB[0], p.bB[0], p.wC[0], p.bC[0],
                             sidx, g, h1s, h2s, redm, feats);
  run_branch<32, 32, 32, 64>(tid, 16, 32, xs, ys, zs, cx, cy, cz,
                             p.wA[1], p.bA[1], p.wB[1], p.bB[1], p.wC[1], p.bC[1],
                             sidx, g, h1s, h2s, redm, feats);
  run_branch<128, 32, 48, 64>(tid, 48, 96, xs, ys, zs, cx, cy, cz,
                              p.wA[2], p.bA[2], p.wB[2], p.bB[2], p.wC[2], p.bC[2],
                              sidx, g, h1s, h2s, redm, feats);

  // ---- head: out = feats . w_out + b_out ----
  float part = feats[tid] * p.w_out[tid];
  if (tid < 32) part += feats[128 + tid] * p.w_out[128 + tid];
#pragma unroll
  for (int off = 32; off > 0; off >>= 1) part += __shfl_xor(part, off, 64);
  if (lane == 0) rsum[wv] = part;
  __syncthreads();
  if (tid == 0) p.out[bid] = rsum[0] + rsum[1] + p.b_out[0];
}

// ================================ launch =====================================
extern "C" void kernel_launch(void* const* d_in, const int* in_sizes, int n_in,
                              void* d_out, int out_size, void* d_ws, size_t ws_size,
                              hipStream_t stream) {
  const float* pcd = (const float*)d_in[0];
  float* ws = (float*)d_ws;
  float* xs = ws;                      // BB*NN
  float* ys = xs + BB * NN;            // BB*NN
  float* zs = ys + BB * NN;            // BB*NN
  float* sp = zs + BB * NN;            // BB*NN
  float* new_xyz = sp + BB * NN;       // BB*SS*3
  float* s_new = new_xyz + BB * SS * 3;  // BB*SS

  prep_kernel<<<(BB * NN + 255) / 256, 256, 0, stream>>>(pcd, xs, ys, zs, sp);
  fps_kernel<<<BB, 512, 0, stream>>>(pcd, new_xyz, s_new);

  KCParams p;
  p.xs = xs; p.ys = ys; p.zs = zs; p.sp = sp;
  p.new_xyz = new_xyz; p.s_new = s_new;
  for (int br = 0; br < 3; ++br) {
    p.wA[br] = (const float*)d_in[1 + 6 * br + 0];
    p.bA[br] = (const float*)d_in[1 + 6 * br + 1];
    p.wB[br] = (const float*)d_in[1 + 6 * br + 2];
    p.bB[br] = (const float*)d_in[1 + 6 * br + 3];
    p.wC[br] = (const float*)d_in[1 + 6 * br + 4];
    p.bC[br] = (const float*)d_in[1 + 6 * br + 5];
  }
  p.w_out = (const float*)d_in[19];
  p.b_out = (const float*)d_in[20];
  p.out = (float*)d_out;

  sa_kernel<<<BB * SS, 128, 0, stream>>>(p);
}

// Round 3
// 1517.923 us; speedup vs baseline: 1.4876x; 1.4876x over previous
//
#include <hip/hip_runtime.h>

#define BB 4
#define NN 8192
#define SS 1024

// ---- exact-IEEE helpers (no FMA contraction: must match numpy fp32 refs) ----
static __device__ __forceinline__ float sq3(float x, float y, float z) {
  return __fadd_rn(__fadd_rn(__fmul_rn(x, x), __fmul_rn(y, y)), __fmul_rn(z, z));
}

// ============================ Kernel A: prep =================================
// SoA split of pcd + per-point squared norm (exact op order: (x^2+y^2)+z^2)
__global__ void prep_kernel(const float* __restrict__ pcd,
                            float* __restrict__ xs, float* __restrict__ ys,
                            float* __restrict__ zs, float* __restrict__ sp) {
  int i = blockIdx.x * 256 + threadIdx.x;
  if (i < BB * NN) {
    float x = pcd[3 * i], y = pcd[3 * i + 1], z = pcd[3 * i + 2];
    xs[i] = x; ys[i] = y; zs[i] = z;
    sp[i] = sq3(x, y, z);
  }
}

// ============================ Kernel B: FPS ==================================
// One block per batch, 256 threads (4 waves = 1/SIMD), 32 points/thread in
// VGPRs. Bitwise-exact reference arithmetic:
//   dist = min(dist, ((dx*dx + dy*dy) + dz*dz))   (no FMA)
//   far  = argmax(dist), first-index tie-break; center emitted BEFORE update.
// One __syncthreads per step: per-wave u64-key butterfly (distbits<<32 |
// (8191-idx) -> max key == max dist, min idx), 4 leader keys via
// double-buffered LDS, then all threads scalar-load the new center from SoA.
__global__ __launch_bounds__(256) void fps_kernel(const float* __restrict__ xs,
                                                  const float* __restrict__ ys,
                                                  const float* __restrict__ zs,
                                                  float* __restrict__ new_xyz,
                                                  float* __restrict__ s_new) {
  const int b = blockIdx.x;
  const float* X = xs + b * NN;
  const float* Y = ys + b * NN;
  const float* Z = zs + b * NN;
  __shared__ unsigned long long wkey[2][4];

  const int tid = threadIdx.x;
  float lx[32], ly[32], lz[32], dst[32];
#pragma unroll
  for (int k = 0; k < 32; ++k) {
    int i = tid + (k << 8);
    lx[k] = X[i]; ly[k] = Y[i]; lz[k] = Z[i];
    dst[k] = 1e10f;
  }
  float cx = X[0], cy = Y[0], cz = Z[0];

  for (int t = 0; t < SS; ++t) {
    if (tid == 0) {
      float* nx = new_xyz + 3 * (b * SS + t);
      nx[0] = cx; nx[1] = cy; nx[2] = cz;
      s_new[b * SS + t] = sq3(cx, cy, cz);
    }
    float lmax = -1.0f;
    int lidx = 0;
#pragma unroll
    for (int k = 0; k < 32; ++k) {
      float dx = __fsub_rn(lx[k], cx);
      float dy = __fsub_rn(ly[k], cy);
      float dz = __fsub_rn(lz[k], cz);
      float d = __fadd_rn(__fadd_rn(__fmul_rn(dx, dx), __fmul_rn(dy, dy)),
                          __fmul_rn(dz, dz));
      d = fminf(dst[k], d);
      dst[k] = d;
      // k ascending => first max => smallest index within this thread
      if (d > lmax) { lmax = d; lidx = tid + (k << 8); }
    }
    // pack: max key == max dist, ties -> larger (8191-idx) == smaller idx
    unsigned long long key =
        ((unsigned long long)__float_as_uint(lmax) << 32) |
        (unsigned)(8191 - lidx);
#pragma unroll
    for (int off = 32; off > 0; off >>= 1) {
      unsigned long long o = __shfl_xor(key, off, 64);
      key = o > key ? o : key;
    }
    if ((tid & 63) == 0) wkey[t & 1][tid >> 6] = key;
    __syncthreads();
    unsigned long long k0 = wkey[t & 1][0], k1 = wkey[t & 1][1];
    unsigned long long k2 = wkey[t & 1][2], k3 = wkey[t & 1][3];
    k0 = k1 > k0 ? k1 : k0;
    k2 = k3 > k2 ? k3 : k2;
    k0 = k2 > k0 ? k2 : k0;
    int gi = 8191 - (int)(k0 & 8191ull);
    int gis = __builtin_amdgcn_readfirstlane(gi);
    cx = X[gis]; cy = Y[gis]; cz = Z[gis];
  }
}

// ===================== Kernel C: ball query + MLP + head =====================
struct KCParams {
  const float* xs; const float* ys; const float* zs; const float* sp;
  const float* new_xyz; const float* s_new;
  const float* wA[3]; const float* bA[3];
  const float* wB[3]; const float* bB[3];
  const float* wC[3]; const float* bC[3];
  const float* w_out; const float* b_out;
  float* out;
};

template <int NS, int C1, int C2, int C3>
__device__ __forceinline__ void run_branch(
    int tid, int off, int fbase,
    const float* __restrict__ xs, const float* __restrict__ ys,
    const float* __restrict__ zs, float cx, float cy, float cz,
    const float* __restrict__ wA, const float* __restrict__ bA,
    const float* __restrict__ wB, const float* __restrict__ bB,
    const float* __restrict__ wC, const float* __restrict__ bC,
    const int* sidx, float (*g)[4], float (*h1)[36], float (*h2)[52],
    float (*redm)[64], float* feats) {
  // gather (grouped - center): continuous op, FMA-free not required
  if (tid < NS) {
    int ip = sidx[off + tid];
    g[tid][0] = xs[ip] - cx;
    g[tid][1] = ys[ip] - cy;
    g[tid][2] = zs[ip] - cz;
  }
  __syncthreads();
  // L1: 3 -> C1, thread = (channel, sample-group)
  {
    const int cc = tid % C1, sg = tid / C1;
    const int G = 128 / C1;
    float wx = wA[cc], wy = wA[C1 + cc], wz = wA[2 * C1 + cc], bb = bA[cc];
    for (int s0 = sg; s0 < NS; s0 += G) {
      float acc = fmaf(g[s0][0], wx, fmaf(g[s0][1], wy, fmaf(g[s0][2], wz, bb)));
      h1[s0][cc] = fmaxf(acc, 0.0f);
    }
  }
  __syncthreads();
  // L2: C1 -> C2, weights in registers, h1 rows broadcast via float4
  {
    const int G = 128 / C2;
    if (tid < G * C2) {
      const int cc = tid % C2, sg = tid / C2;
      float wr[C1];
#pragma unroll
      for (int k = 0; k < C1; ++k) wr[k] = wB[k * C2 + cc];
      float bb = bB[cc];
#pragma unroll 2
      for (int s0 = sg; s0 < NS; s0 += G) {
        const float4* hr = (const float4*)(&h1[s0][0]);
        float acc = bb;
#pragma unroll
        for (int k4 = 0; k4 < C1 / 4; ++k4) {
          float4 hv = hr[k4];
          acc = fmaf(hv.x, wr[4 * k4 + 0], acc);
          acc = fmaf(hv.y, wr[4 * k4 + 1], acc);
          acc = fmaf(hv.z, wr[4 * k4 + 2], acc);
          acc = fmaf(hv.w, wr[4 * k4 + 3], acc);
        }
        h2[s0][cc] = fmaxf(acc, 0.0f);
      }
    }
  }
  __syncthreads();
  // L3 + maxpool over samples: thread owns an output channel
  {
    const int G = 128 / C3;
    const int cc = tid % C3, sg = tid / C3;
    float wr[C2];
#pragma unroll
    for (int k = 0; k < C2; ++k) wr[k] = wC[k * C3 + cc];
    float bb = bC[cc];
    float pm = -1e30f;
#pragma unroll 2
    for (int s0 = sg; s0 < NS; s0 += G) {
      const float4* hr = (const float4*)(&h2[s0][0]);
      float acc = bb;
#pragma unroll
      for (int k4 = 0; k4 < C2 / 4; ++k4) {
        float4 hv = hr[k4];
        acc = fmaf(hv.x, wr[4 * k4 + 0], acc);
        acc = fmaf(hv.y, wr[4 * k4 + 1], acc);
        acc = fmaf(hv.z, wr[4 * k4 + 2], acc);
        acc = fmaf(hv.w, wr[4 * k4 + 3], acc);
      }
      pm = fmaxf(pm, fmaxf(acc, 0.0f));
    }
    redm[sg][cc] = pm;
  }
  __syncthreads();
  if (tid < C3) {
    float m = redm[0][tid];
#pragma unroll
    for (int gg = 1; gg < 128 / C3; ++gg) m = fmaxf(m, redm[gg][tid]);
    feats[fbase + tid] = m;
  }
  __syncthreads();
}

__global__ __launch_bounds__(128) void sa_kernel(KCParams p) {
  const int bid = blockIdx.x;
  const int b = bid >> 10;
  const int tid = threadIdx.x;
  const int lane = tid & 63;
  const int wv = tid >> 6;

  __shared__ __align__(16) float g[128][4];
  __shared__ __align__(16) float h1s[128][36];
  __shared__ __align__(16) float h2s[128][52];
  __shared__ int sidx[176];
  __shared__ int lid0[2][16];
  __shared__ int lid1[2][32];
  __shared__ int lid2[2][128];
  __shared__ int scnt[2][3];
  __shared__ float feats[160];
  __shared__ __align__(16) float redm[4][64];
  __shared__ float rsum[2];

  const float* xs = p.xs + b * NN;
  const float* ys = p.ys + b * NN;
  const float* zs = p.zs + b * NN;
  const float* sp = p.sp + b * NN;
  const float cx = p.new_xyz[3 * bid];
  const float cy = p.new_xyz[3 * bid + 1];
  const float cz = p.new_xyz[3 * bid + 2];
  const float snew = p.s_new[bid];

  // ---- ball query: two waves scan the two halves, ordered compaction ----
  {
    const float R2_0 = (float)(0.1 * 0.1);
    const float R2_1 = (float)(0.2 * 0.2);
    const float R2_2 = (float)(0.4 * 0.4);
    const unsigned long long below = (1ull << lane) - 1ull;
    int c0 = 0, c1 = 0, c2 = 0;
    int pt = wv * 4096 + lane;
    float x = xs[pt], y = ys[pt], z = zs[pt], s2v = sp[pt];
    for (int it = 0; it < 64; ++it) {
      float xx = x, yy = y, zz = z, ss = s2v;
      if (it < 63) {  // one-deep prefetch
        int q = pt + 64;
        x = xs[q]; y = ys[q]; z = zs[q]; s2v = sp[q];
      }
      // Reference einsum('bsd,bnd->bsn') contraction (K=3) is computed with
      // FMA on every candidate backend (numpy npyv_muladd / Eigen / cublas):
      //   dot = fma(z*cz, fma(y*cy, rn(x*cx)))
      // while the norm sums are materialized-then-reduced (no FMA).
      float dt = fmaf(zz, cz, fmaf(yy, cy, __fmul_rn(xx, cx)));
      float d = __fsub_rn(__fadd_rn(snew, ss), __fmul_rn(2.0f, dt));
      bool m2 = d <= R2_2;
      unsigned long long bm = __ballot(m2);
      if (m2) { int r = c2 + __popcll(bm & below); if (r < 128) lid2[wv][r] = pt; }
      c2 += __popcll(bm);
      bool m1 = d <= R2_1;
      bm = __ballot(m1);
      if (m1) { int r = c1 + __popcll(bm & below); if (r < 32) lid1[wv][r] = pt; }
      c1 += __popcll(bm);
      bool m0 = d <= R2_0;
      bm = __ballot(m0);
      if (m0) { int r = c0 + __popcll(bm & below); if (r < 16) lid0[wv][r] = pt; }
      c0 += __popcll(bm);
      pt += 64;
      if (c0 >= 16 && c1 >= 32 && c2 >= 128) break;
    }
    if (lane == 0) {
      scnt[wv][0] = c0 < 16 ? c0 : 16;
      scnt[wv][1] = c1 < 32 ? c1 : 32;
      scnt[wv][2] = c2 < 128 ? c2 : 128;
    }
  }
  __syncthreads();
  // merge the two halves' ordered lists; pad with first match
  {
    int a0 = scnt[0][0], a1 = scnt[0][1], a2 = scnt[0][2];
    int b0 = scnt[1][0], b1 = scnt[1][1], b2 = scnt[1][2];
    int n0 = min(a0 + b0, 16), n1 = min(a1 + b1, 32), n2 = min(a2 + b2, 128);
    int f0 = a0 ? lid0[0][0] : lid0[1][0];
    int f1 = a1 ? lid1[0][0] : lid1[1][0];
    int f2 = a2 ? lid2[0][0] : lid2[1][0];
    for (int j = tid; j < 176; j += 128) {
      int v;
      if (j < 16) {
        int sl = j;
        v = sl < a0 ? lid0[0][sl] : (sl < n0 ? lid0[1][sl - a0] : f0);
      } else if (j < 48) {
        int sl = j - 16;
        v = sl < a1 ? lid1[0][sl] : (sl < n1 ? lid1[1][sl - a1] : f1);
      } else {
        int sl = j - 48;
        v = sl < a2 ? lid2[0][sl] : (sl < n2 ? lid2[1][sl - a2] : f2);
      }
      sidx[j] = v;
    }
  }
  __syncthreads();

  run_branch<16, 16, 16, 32>(tid, 0, 0, xs, ys, zs, cx, cy, cz,
                             p.wA[0], p.bA[0], p.wB[0], p.bB[0], p.wC[0], p.bC[0],
                             sidx, g, h1s, h2s, redm, feats);
  run_branch<32, 32, 32, 64>(tid, 16, 32, xs, ys, zs, cx, cy, cz,
                             p.wA[1], p.bA[1], p.wB[1], p.bB[1], p.wC[1], p.bC[1],
                             sidx, g, h1s, h2s, redm, feats);
  run_branch<128, 32, 48, 64>(tid, 48, 96, xs, ys, zs, cx, cy, cz,
                              p.wA[2], p.bA[2], p.wB[2], p.bB[2], p.wC[2], p.bC[2],
                              sidx, g, h1s, h2s, redm, feats);

  // ---- head: out = feats . w_out + b_out ----
  float part = feats[tid] * p.w_out[tid];
  if (tid < 32) part += feats[128 + tid] * p.w_out[128 + tid];
#pragma unroll
  for (int off = 32; off > 0; off >>= 1) part += __shfl_xor(part, off, 64);
  if (lane == 0) rsum[wv] = part;
  __syncthreads();
  if (tid == 0) p.out[bid] = rsum[0] + rsum[1] + p.b_out[0];
}

// ================================ launch =====================================
extern "C" void kernel_launch(void* const* d_in, const int* in_sizes, int n_in,
                              void* d_out, int out_size, void* d_ws, size_t ws_size,
                              hipStream_t stream) {
  const float* pcd = (const float*)d_in[0];
  float* ws = (float*)d_ws;
  float* xs = ws;                      // BB*NN
  float* ys = xs + BB * NN;            // BB*NN
  float* zs = ys + BB * NN;            // BB*NN
  float* sp = zs + BB * NN;            // BB*NN
  float* new_xyz = sp + BB * NN;       // BB*SS*3
  float* s_new = new_xyz + BB * SS * 3;  // BB*SS

  prep_kernel<<<(BB * NN + 255) / 256, 256, 0, stream>>>(pcd, xs, ys, zs, sp);
  fps_kernel<<<BB, 256, 0, stream>>>(xs, ys, zs, new_xyz, s_new);

  KCParams p;
  p.xs = xs; p.ys = ys; p.zs = zs; p.sp = sp;
  p.new_xyz = new_xyz; p.s_new = s_new;
  for (int br = 0; br < 3; ++br) {
    p.wA[br] = (const float*)d_in[1 + 6 * br + 0];
    p.bA[br] = (const float*)d_in[1 + 6 * br + 1];
    p.wB[br] = (const float*)d_in[1 + 6 * br + 2];
    p.bB[br] = (const float*)d_in[1 + 6 * br + 3];
    p.wC[br] = (const float*)d_in[1 + 6 * br + 4];
    p.bC[br] = (const float*)d_in[1 + 6 * br + 5];
  }
  p.w_out = (const float*)d_in[19];
  p.b_out = (const float*)d_in[20];
  p.out = (float*)d_out;

  sa_kernel<<<BB * SS, 128, 0, stream>>>(p);
}